// Round 12
// baseline (266.169 us; speedup 1.0000x reference)
//
#include <hip/hip_runtime.h>
#include <math.h>

#define T_DIM 16384
#define A_DIM 128
#define K_DIM 128
#define N_STEPS 16
#define E_DIM 126
#define NSEQ 4

// tiles: 16 atoms x 256 t -> 8 atiles x 64 ttiles = 512 tiles/seq
#define ATI 16
#define TT 256
#define NPT 512
#define NCB 32          // compute blocks/seq: 8 atiles x 2 halves x 2 parities
#define HB 8192         // half length in t
#define RL_LEN 8319     // local residual coverage: [base-64, base+8255]
#define RL_PAD 8608     // PIDX(8323)=8583 max touched; margin
#define SS_LEN 383      // staged window (step_full)
#define SS_PAD 404

#define PIDX(i) ((i) + ((i) >> 5))   // +1 pad per 32 dwords

// order-preserving pack: bigger u64 == (bigger value, then smaller flat idx).
// Never 0 for finite fm values -> 0 is the "empty mailbox" sentinel.
__device__ inline unsigned long long pack_vi(float v, int fi) {
    unsigned int b = __float_as_uint(v);
    b = (b & 0x80000000u) ? ~b : (b | 0x80000000u);
    return ((unsigned long long)b << 32) | (unsigned int)(~fi);
}
__device__ inline void unpack_vi(unsigned long long p, float* v, int* fi) {
    unsigned int lo = (unsigned int)(p & 0xffffffffu);
    unsigned int b = (unsigned int)(p >> 32);
    unsigned int fb = (b & 0x80000000u) ? (b & 0x7fffffffu) : ~b;
    *v = __uint_as_float(fb);
    *fi = (int)(~lo);
}

__device__ inline unsigned long long u64max(unsigned long long a, unsigned long long b) {
    return a > b ? a : b;
}

// ---------------------------------------------------------------------------
// blocks 0..127: d_unit rows; 128..383: res init; 384: zero cnt + slots
__global__ __launch_bounds__(256) void k_prep(
    const float* __restrict__ d, const float* __restrict__ a,
    const float* __restrict__ b, float* __restrict__ du,
    float* __restrict__ res, int* __restrict__ cnt,
    unsigned long long* __restrict__ wslot, int* __restrict__ acnt) {
    int blk = blockIdx.x, tid = threadIdx.x;
    if (blk < 128) {
        __shared__ float s[128];
        float v = 0.0f;
        if (tid < 128) { v = d[blk * K_DIM + tid]; s[tid] = v * v; }
        __syncthreads();
        for (int off = 64; off > 0; off >>= 1) {
            if (tid < off) s[tid] += s[tid + off];
            __syncthreads();
        }
        if (tid < 128) du[blk * K_DIM + tid] = v / (sqrtf(s[0]) + 1e-8f);
    } else if (blk < 384) {
        int i = (blk - 128) * 256 + tid;      // 0..65535
        res[i] = (i < 2 * T_DIM) ? a[i] : b[i - 2 * T_DIM];
    } else {
        if (tid < NSEQ) cnt[tid] = 0;
        if (tid < (N_STEPS - 1) * NSEQ) { wslot[tid] = 0ULL; acnt[tid] = 0; }
    }
}

// ---------------------------------------------------------------------------
// 16a x 256t tile engine (R10-proven). du via wave-uniform s_load float4;
// res via padded scalar b32 sliding window (zero conflicts). Per-acc FMA
// chain = k ascending -> bit-identical fm. Block argmax via shfl + red4.
__device__ inline unsigned long long tile_compute(
    const float* __restrict__ duP, const float* __restrict__ rsh,
    int L0, int a_lo, int t_lo, int tid, unsigned long long* red4) {

    float acc[4][4];
    #pragma unroll
    for (int i = 0; i < 4; i++)
        #pragma unroll
        for (int j = 0; j < 4; j++) acc[i][j] = 0.0f;

    float r[8];
    #pragma unroll
    for (int m = 0; m < 8; m++) r[m] = rsh[PIDX(L0 + m)];

    #pragma unroll 4
    for (int k = 0; k < K_DIM; k += 4) {
        float dA[4][4];
        #pragma unroll
        for (int i = 0; i < 4; i++)
            *(float4*)dA[i] = *(const float4*)(duP + i * K_DIM + k);  // uniform s_load
        #pragma unroll
        for (int dk = 0; dk < 4; dk++) {
            #pragma unroll
            for (int i = 0; i < 4; i++) {
                float s = dA[i][dk];
                #pragma unroll
                for (int j = 0; j < 4; j++)
                    acc[i][j] = fmaf(s, r[j + dk], acc[i][j]);   // k ascending per acc
            }
        }
        r[0] = r[4]; r[1] = r[5]; r[2] = r[6]; r[3] = r[7];
        #pragma unroll
        for (int m = 0; m < 4; m++) r[4 + m] = rsh[PIDX(L0 + k + 8 + m)];
    }

    float bv = -INFINITY;
    int bi = 0x7fffffff;
    #pragma unroll
    for (int i = 0; i < 4; i++) {          // ascending flat index scan
        int a = a_lo + i;
        #pragma unroll
        for (int j = 0; j < 4; j++) {
            int fi = a * T_DIM + t_lo + j;
            float v = acc[i][j];
            if (v > bv || (v == bv && fi < bi)) { bv = v; bi = fi; }
        }
    }
    #pragma unroll
    for (int off = 32; off > 0; off >>= 1) {
        float v2 = __shfl_down(bv, off);
        int   i2 = __shfl_down(bi, off);
        if (v2 > bv || (v2 == bv && i2 < bi)) { bv = v2; bi = i2; }
    }
    if ((tid & 63) == 0) red4[tid >> 6] = pack_vi(bv, bi);
    __syncthreads();
    if (tid == 0) {
        unsigned long long m = red4[0];
        #pragma unroll
        for (int w = 1; w < 4; w++) if (red4[w] > m) m = red4[w];
        red4[0] = m;
    }
    __syncthreads();
    return red4[0];
}

// ---------------------------------------------------------------------------
// step 0: 512 blocks/seq; staged padded window; last arrival reduces pmax,
// finalizes step 0 into global res/emb, publishes step-1 dirty window.
__global__ __launch_bounds__(256) void k_step_full(
    float* __restrict__ res, const float* __restrict__ du,
    const float* __restrict__ ae, float* __restrict__ emb,
    unsigned long long* __restrict__ pmax, int* __restrict__ cnt,
    int* __restrict__ dirty0) {

    int seq = blockIdx.y;
    int blk = blockIdx.x;                 // 0..511 = atile*64 + ttile
    int a_base = (blk >> 6) * ATI;
    int t0 = (blk & 63) * TT;
    int tid = threadIdx.x;

    __shared__ float rsh[SS_PAD];
    __shared__ unsigned long long red4[4];
    __shared__ unsigned long long pm_sh[256];
    __shared__ int last_flag;

    const float* resS = res + seq * T_DIM;
    for (int i = tid; i < SS_LEN; i += 256) {
        int t = t0 - 64 + i;
        rsh[PIDX(i)] = (t >= 0 && t < T_DIM) ? resS[t] : 0.0f;
    }
    __syncthreads();

    int tg = tid & 63;
    int ag = __builtin_amdgcn_readfirstlane(tid >> 6);
    unsigned long long p = tile_compute(du + (a_base + ag * 4) * K_DIM, rsh,
                                        4 * tg, a_base + ag * 4, t0 + 4 * tg,
                                        tid, red4);
    if (tid == 0) {
        pmax[seq * NPT + blk] = p;
        __threadfence();
        last_flag = (atomicAdd(&cnt[seq], 1) == NPT - 1);
    }
    __syncthreads();
    if (!last_flag) return;

    __threadfence();
    {
        unsigned long long m0 = pmax[seq * NPT + tid];
        unsigned long long m1 = pmax[seq * NPT + 256 + tid];
        pm_sh[tid] = u64max(m0, m1);
    }
    __syncthreads();
    for (int off = 128; off > 0; off >>= 1) {
        if (tid < off) pm_sh[tid] = u64max(pm_sh[tid], pm_sh[tid + off]);
        __syncthreads();
    }
    float value; int fi;
    unpack_vi(pm_sh[0], &value, &fi);
    int ai = fi >> 14;
    int ti = fi & (T_DIM - 1);
    int pos_idx = value > 0.0f ? ti : 0;
    int atom_idx = value > 0.0f ? ai : 0;

    float* e = emb + (seq * N_STEPS + 0) * 128;
    if (tid == 0) {
        e[0] = ((float)pos_idx / (float)(T_DIM - 1)) * 20.0f;
        e[1] = value;
        int nlo = ti - (K_DIM - 1); if (nlo < 0) nlo = 0;
        int nhi = ti + K_DIM;       if (nhi > T_DIM) nhi = T_DIM;
        dirty0[seq * 2 + 0] = nlo;
        dirty0[seq * 2 + 1] = nhi;
    }
    if (tid >= 2 && tid < 2 + E_DIM) e[tid] = ae[atom_idx * E_DIM + tid - 2];
    if (tid >= 128) {
        int k = tid - 128;
        int t = ti + k - K_DIM / 2;
        if (t >= 0 && t < T_DIM) {
            float r = res[seq * T_DIM + t];
            res[seq * T_DIM + t] = __fsub_rn(r, __fmul_rn(value, du[ai * K_DIM + k]));
        }
    }
}

// ---------------------------------------------------------------------------
// persistent steps 1..15. Single-hop single-slot protocol:
// every block publishes its block-max (over 16 owned tiles) via atomicMax on
// ONE u64 winner slot per (step,seq), then bumps an arrival counter (ordered
// behind the max by a data dependency on the returned old value -> vmcnt
// wait, no fence). All blocks poll ONLY the counter (1 lane, backoff), then
// read the final slot once. Winner msg = complete update; apply locally.
__global__ __launch_bounds__(256) void k_inc(
    float* __restrict__ res, const float* __restrict__ du,
    const float* __restrict__ ae, float* __restrict__ emb,
    const unsigned long long* __restrict__ pmax,
    unsigned long long* __restrict__ wslot, int* __restrict__ acnt,
    const int* __restrict__ dirty0) {

    int seq = blockIdx.y;
    int blk = blockIdx.x;                 // 0..31
    int atile = blk >> 2;                 // 0..7
    int half = (blk >> 1) & 1;
    int par = blk & 1;
    int a_base = atile * ATI;
    int base = half * HB;
    int tid = threadIdx.x;

    __shared__ float resL[RL_PAD];             // ~34 KB padded local residual
    __shared__ unsigned long long red4[4];
    __shared__ unsigned long long tmax[16];    // owned ttiles: half*32+par+2m
    __shared__ unsigned long long wsh;

    const float* resG = res + seq * T_DIM;
    for (int i4 = tid * 4; i4 < RL_LEN; i4 += 1024) {
        int t = base - 64 + i4;
        if (t >= 0 && t + 3 < T_DIM && i4 + 3 < RL_LEN) {
            float4 v = *(const float4*)&resG[t];
            resL[PIDX(i4 + 0)] = v.x; resL[PIDX(i4 + 1)] = v.y;
            resL[PIDX(i4 + 2)] = v.z; resL[PIDX(i4 + 3)] = v.w;
        } else {
            for (int m = 0; m < 4 && i4 + m < RL_LEN; m++) {
                int t2 = t + m;
                resL[PIDX(i4 + m)] = (t2 >= 0 && t2 < T_DIM) ? resG[t2] : 0.0f;
            }
        }
    }
    if (tid < 16) {
        int tt = half * 32 + par + 2 * tid;
        tmax[tid] = pmax[seq * NPT + atile * 64 + tt];
    }
    int lo = dirty0[seq * 2 + 0];
    int hi = dirty0[seq * 2 + 1];
    __syncthreads();

    for (int step = 1; step < N_STEPS; step++) {
        int T0 = lo >> 8, T1 = T0 + 1;
        int cand = -1;
        if (((T0 & 1) == par) && ((T0 >> 5) == half)) cand = T0;
        else if (T1 < 64 && ((T1 & 1) == par) && ((T1 >> 5) == half) &&
                 T1 * TT < hi) cand = T1;

        if (cand >= 0) {
            int t0 = cand * TT;
            int tg = tid & 63;
            int ag = __builtin_amdgcn_readfirstlane(tid >> 6);
            unsigned long long p = tile_compute(
                du + (a_base + ag * 4) * K_DIM, resL,
                (t0 - base) + 4 * tg, a_base + ag * 4, t0 + 4 * tg, tid, red4);
            if (tid == 0) tmax[(cand - half * 32 - par) >> 1] = p;
        }
        int idx = (step - 1) * NSEQ + seq;
        if (tid == 0) {
            unsigned long long m = tmax[0];
            #pragma unroll
            for (int j = 1; j < 16; j++) m = u64max(m, tmax[j]);
            unsigned long long old = atomicMax(&wslot[idx], m);
            // data dep on 'old' -> add issues only after max completed at L2
            if (old != ~0ULL) atomicAdd(&acnt[idx], 1);
            int c = __hip_atomic_load(&acnt[idx], __ATOMIC_RELAXED,
                                      __HIP_MEMORY_SCOPE_AGENT);
            while (c < NCB) {
                __builtin_amdgcn_s_sleep(4);
                c = __hip_atomic_load(&acnt[idx], __ATOMIC_RELAXED,
                                      __HIP_MEMORY_SCOPE_AGENT);
            }
            // idx + (c - NCB) == idx; data dep keeps this load after the loop
            wsh = __hip_atomic_load(&wslot[idx + (c - NCB)], __ATOMIC_RELAXED,
                                    __HIP_MEMORY_SCOPE_AGENT);
        }
        __syncthreads();

        float value; int fi;
        unpack_vi(wsh, &value, &fi);
        int ti = fi & (T_DIM - 1);
        int ai = fi >> 14;

        if (blk == 0) {   // emb row for this step
            int pos_idx = value > 0.0f ? ti : 0;
            int atom_idx = value > 0.0f ? ai : 0;
            float* e = emb + (seq * N_STEPS + step) * 128;
            if (tid == 0) {
                e[0] = ((float)pos_idx / (float)(T_DIM - 1)) * 20.0f;
                e[1] = value;
            }
            if (tid >= 2 && tid < 128) e[tid] = ae[atom_idx * E_DIM + tid - 2];
        }
        // apply winner's update to local residual (mul-then-sub, step order)
        if (tid < 128) {
            int t = ti - K_DIM / 2 + tid;
            if (t >= 0 && t < T_DIM) {
                int L = t - base + 64;
                if (L >= 0 && L < RL_LEN) {
                    float r = resL[PIDX(L)];
                    resL[PIDX(L)] = __fsub_rn(r, __fmul_rn(value, du[ai * K_DIM + tid]));
                }
            }
        }
        __syncthreads();
        lo = ti - (K_DIM - 1); if (lo < 0) lo = 0;
        hi = ti + K_DIM;       if (hi > T_DIM) hi = T_DIM;
    }

    // final residual write-back (one block per half per seq) for k_tail
    if (atile == 0 && par == 0) {
        float* resW = res + seq * T_DIM + base;
        for (int t = tid; t < HB; t += 256) resW[t] = resL[PIDX(t + 64)];
    }
}

// ---------------------------------------------------------------------------
// norms + ordering + loss; 1 block x 1024 threads
__global__ __launch_bounds__(1024) void k_tail(
    const float* __restrict__ res, const float* __restrict__ emb,
    const float* __restrict__ proj, float* __restrict__ out) {
    int tid = threadIdx.x;
    __shared__ float sh[1024];
    __shared__ float norms[NSEQ];
    __shared__ float keys[NSEQ][N_STEPS];
    __shared__ int   order[NSEQ][N_STEPS];

    {
        int seq = tid >> 8;
        int ln  = tid & 255;
        const float4* r4 = (const float4*)(res + seq * T_DIM);
        float s = 0.0f;
        #pragma unroll
        for (int j = 0; j < 16; j++) {
            float4 v = r4[j * 256 + ln];
            s = fmaf(v.x, v.x, s); s = fmaf(v.y, v.y, s);
            s = fmaf(v.z, v.z, s); s = fmaf(v.w, v.w, s);
        }
        sh[tid] = s;
        __syncthreads();
        for (int off = 128; off > 0; off >>= 1) {
            if (ln < off) sh[tid] += sh[tid + off];
            __syncthreads();
        }
        if (ln == 0) norms[seq] = sqrtf(sh[tid]);
        __syncthreads();
    }
    {
        int pair = tid >> 4;
        int seq = pair >> 4, st = pair & 15;
        int ln = tid & 15;
        const float* e = emb + (seq * N_STEPS + st) * 128 + ln * 8;
        const float* pr = proj + ln * 8;
        float kk = 0.0f;
        #pragma unroll
        for (int dd = 0; dd < 8; dd++) kk = fmaf(e[dd], pr[dd], kk);
        sh[tid] = kk;
        __syncthreads();
        for (int off = 8; off > 0; off >>= 1) {
            if (ln < off) sh[tid] += sh[tid + off];
            __syncthreads();
        }
        if (ln == 0) keys[seq][st] = sh[tid];
        __syncthreads();
    }
    if (tid < NSEQ) {
        int ord[N_STEPS];
        for (int i = 0; i < N_STEPS; i++) ord[i] = i;
        for (int i = 1; i < N_STEPS; i++) {
            int oi = ord[i];
            float kv = keys[tid][oi];
            int j = i - 1;
            while (j >= 0 && keys[tid][ord[j]] > kv) { ord[j + 1] = ord[j]; j--; }
            ord[j + 1] = oi;
        }
        for (int i = 0; i < N_STEPS; i++) order[tid][i] = ord[i];
    }
    __syncthreads();
    float s = 0.0f;
    #pragma unroll
    for (int t = 0; t < 4; t++) {
        int idx = tid + t * 1024;
        int b  = idx >> 11;
        int st = (idx >> 7) & 15;
        int dd = idx & 127;
        float va = emb[((b    ) * N_STEPS + order[b    ][st]) * 128 + dd];
        float vb = emb[((2 + b) * N_STEPS + order[2 + b][st]) * 128 + dd];
        float df = va - vb;
        s = fmaf(df, df, s);
    }
    sh[tid] = s;
    __syncthreads();
    for (int off = 512; off > 0; off >>= 1) {
        if (tid < off) sh[tid] += sh[tid + off];
        __syncthreads();
    }
    if (tid == 0) {
        float mse = sh[0] / 4096.0f;
        float mad = 0.5f * (fabsf(norms[0] - norms[2]) + fabsf(norms[1] - norms[3]));
        out[0] = mse + mad;
    }
}

// ---------------------------------------------------------------------------
extern "C" void kernel_launch(void* const* d_in, const int* in_sizes, int n_in,
                              void* d_out, int out_size, void* d_ws, size_t ws_size,
                              hipStream_t stream) {
    const float* a    = (const float*)d_in[0];
    const float* b    = (const float*)d_in[1];
    const float* d    = (const float*)d_in[2];
    const float* ae   = (const float*)d_in[3];
    const float* proj = (const float*)d_in[4];
    float* out = (float*)d_out;

    float* ws  = (float*)d_ws;
    float* res = ws;                              // 65536 f
    float* du  = res + NSEQ * T_DIM;              // 16384 f
    float* emb = du + A_DIM * K_DIM;              // 8192 f
    unsigned long long* pmax  = (unsigned long long*)(emb + NSEQ * N_STEPS * 128); // 2048 u64
    unsigned long long* wslot = pmax + NSEQ * NPT;                     // 60 u64
    int* acnt   = (int*)(wslot + (N_STEPS - 1) * NSEQ);                // 60 ints
    int* cnt    = acnt + (N_STEPS - 1) * NSEQ;                         // 4
    int* dirty0 = cnt + NSEQ;                                          // 8 ints

    k_prep<<<385, 256, 0, stream>>>(d, a, b, du, res, cnt, wslot, acnt);

    dim3 gfull(NPT, NSEQ);
    k_step_full<<<gfull, 256, 0, stream>>>(res, du, ae, emb, pmax, cnt, dirty0);

    dim3 ginc(NCB, NSEQ);
    k_inc<<<ginc, 256, 0, stream>>>(res, du, ae, emb, pmax, wslot, acnt, dirty0);

    k_tail<<<1, 1024, 0, stream>>>(res, emb, proj, out);
}

// Round 13
// 248.167 us; speedup vs baseline: 1.0725x; 1.0725x over previous
//
#include <hip/hip_runtime.h>
#include <math.h>

#define T_DIM 16384
#define A_DIM 128
#define K_DIM 128
#define N_STEPS 16
#define E_DIM 126
#define NSEQ 4

// tiles: 8 atoms x 256 t -> 16 atiles x 64 ttiles = 1024 tiles/seq
#define ATI 8
#define NAT 16
#define TT 256
#define NTT 64
#define NPT 1024
#define NCB 64          // compute blocks/seq: 16 atiles x 2 halves x 2 parities
#define HB 8192         // half length in t
#define RL_LEN 8319     // local residual coverage: [base-64, base+8255]
#define RL_PAD 8608
#define SS_LEN 383      // staged window (step_full)
#define SS_PAD 404

#define PIDX(i) ((i) + ((i) >> 5))   // +1 pad per 32 dwords: conflict-free 4t/lane

// order-preserving pack: bigger u64 == (bigger value, then smaller flat idx).
// Never 0 for finite fm values -> 0 is the "empty mailbox" sentinel.
__device__ inline unsigned long long pack_vi(float v, int fi) {
    unsigned int b = __float_as_uint(v);
    b = (b & 0x80000000u) ? ~b : (b | 0x80000000u);
    return ((unsigned long long)b << 32) | (unsigned int)(~fi);
}
__device__ inline void unpack_vi(unsigned long long p, float* v, int* fi) {
    unsigned int lo = (unsigned int)(p & 0xffffffffu);
    unsigned int b = (unsigned int)(p >> 32);
    unsigned int fb = (b & 0x80000000u) ? (b & 0x7fffffffu) : ~b;
    *v = __uint_as_float(fb);
    *fi = (int)(~lo);
}
__device__ inline unsigned long long u64max(unsigned long long a, unsigned long long b) {
    return a > b ? a : b;
}

// ---------------------------------------------------------------------------
// blocks 0..127: d_unit rows; block 128: zero control state
__global__ __launch_bounds__(256) void k_prep(
    const float* __restrict__ d, float* __restrict__ du,
    unsigned long long* __restrict__ zeroU, int* __restrict__ cnt,
    float* __restrict__ norm2) {
    int blk = blockIdx.x, tid = threadIdx.x;
    if (blk < 128) {
        __shared__ float s[128];
        float v = 0.0f;
        if (tid < 128) { v = d[blk * K_DIM + tid]; s[tid] = v * v; }
        __syncthreads();
        for (int off = 64; off > 0; off >>= 1) {
            if (tid < off) s[tid] += s[tid + off];
            __syncthreads();
        }
        if (tid < 128) du[blk * K_DIM + tid] = v / (sqrtf(s[0]) + 1e-8f);
    } else {
        // dslots(1920) + wslot(60) + w0slot(4) = 1984 u64, contiguous
        for (int i = tid; i < 1984; i += 256) zeroU[i] = 0ULL;
        if (tid < NSEQ) { cnt[tid] = 0; norm2[tid] = 0.0f; }
    }
}

// ---------------------------------------------------------------------------
// 8a x 256t tile engine: du via wave-uniform s_load float4 (2 atoms/wave);
// res via padded scalar b32 sliding window (zero conflicts). Per-acc FMA
// chain = k ascending, same operand order -> bit-identical fm values.
__device__ inline unsigned long long tile_compute(
    const float* __restrict__ duP, const float* __restrict__ rsh,
    int L0, int a_lo, int t_lo, int tid, unsigned long long* red4) {

    float acc[2][4];
    #pragma unroll
    for (int i = 0; i < 2; i++)
        #pragma unroll
        for (int j = 0; j < 4; j++) acc[i][j] = 0.0f;

    float r[8];
    #pragma unroll
    for (int m = 0; m < 8; m++) r[m] = rsh[PIDX(L0 + m)];

    #pragma unroll 4
    for (int k = 0; k < K_DIM; k += 4) {
        float dA[2][4];
        #pragma unroll
        for (int i = 0; i < 2; i++)
            *(float4*)dA[i] = *(const float4*)(duP + i * K_DIM + k);  // uniform s_load
        #pragma unroll
        for (int dk = 0; dk < 4; dk++) {
            #pragma unroll
            for (int i = 0; i < 2; i++) {
                float s = dA[i][dk];
                #pragma unroll
                for (int j = 0; j < 4; j++)
                    acc[i][j] = fmaf(s, r[j + dk], acc[i][j]);   // k ascending per acc
            }
        }
        r[0] = r[4]; r[1] = r[5]; r[2] = r[6]; r[3] = r[7];
        #pragma unroll
        for (int m = 0; m < 4; m++) r[4 + m] = rsh[PIDX(L0 + k + 8 + m)];
    }

    float bv = -INFINITY;
    int bi = 0x7fffffff;
    #pragma unroll
    for (int i = 0; i < 2; i++) {          // ascending flat index scan
        int a = a_lo + i;
        #pragma unroll
        for (int j = 0; j < 4; j++) {
            int fi = a * T_DIM + t_lo + j;
            float v = acc[i][j];
            if (v > bv || (v == bv && fi < bi)) { bv = v; bi = fi; }
        }
    }
    #pragma unroll
    for (int off = 32; off > 0; off >>= 1) {
        float v2 = __shfl_down(bv, off);
        int   i2 = __shfl_down(bi, off);
        if (v2 > bv || (v2 == bv && i2 < bi)) { bv = v2; bi = i2; }
    }
    if ((tid & 63) == 0) red4[tid >> 6] = pack_vi(bv, bi);
    __syncthreads();
    if (tid == 0) {
        unsigned long long m = red4[0];
        #pragma unroll
        for (int w = 1; w < 4; w++) m = u64max(m, red4[w]);
        red4[0] = m;
    }
    __syncthreads();
    return red4[0];
}

// ---------------------------------------------------------------------------
// step 0: 1024 blocks/seq staged directly from inputs (res == input at step 0).
// Last arrival reduces pmax, writes emb row 0, publishes winner0 + dirty0.
// Global res is NEVER materialized.
__global__ __launch_bounds__(256) void k_step_full(
    const float* __restrict__ a, const float* __restrict__ b,
    const float* __restrict__ du, const float* __restrict__ ae,
    float* __restrict__ emb, unsigned long long* __restrict__ pmax,
    int* __restrict__ cnt, int* __restrict__ dirty0,
    unsigned long long* __restrict__ w0slot) {

    int seq = blockIdx.y;
    int blk = blockIdx.x;                 // 0..1023 = atile*64 + ttile
    int a_base = (blk >> 6) * ATI;
    int t0 = (blk & 63) * TT;
    int tid = threadIdx.x;

    __shared__ float rsh[SS_PAD];
    __shared__ unsigned long long red4[4];
    __shared__ unsigned long long pm_sh[256];
    __shared__ int last_flag;

    const float* x = (seq < 2 ? a : b) + (seq & 1) * T_DIM;
    for (int i = tid; i < SS_LEN; i += 256) {
        int t = t0 - 64 + i;
        rsh[PIDX(i)] = (t >= 0 && t < T_DIM) ? x[t] : 0.0f;
    }
    __syncthreads();

    int tg = tid & 63;
    int ag = __builtin_amdgcn_readfirstlane(tid >> 6);
    unsigned long long p = tile_compute(du + (a_base + ag * 2) * K_DIM, rsh,
                                        4 * tg, a_base + ag * 2, t0 + 4 * tg,
                                        tid, red4);
    if (tid == 0) {
        pmax[seq * NPT + blk] = p;
        __threadfence();
        last_flag = (atomicAdd(&cnt[seq], 1) == NPT - 1);
    }
    __syncthreads();
    if (!last_flag) return;

    __threadfence();
    {
        unsigned long long m = u64max(pmax[seq * NPT + tid],
                                      pmax[seq * NPT + 256 + tid]);
        m = u64max(m, u64max(pmax[seq * NPT + 512 + tid],
                             pmax[seq * NPT + 768 + tid]));
        pm_sh[tid] = m;
    }
    __syncthreads();
    for (int off = 128; off > 0; off >>= 1) {
        if (tid < off) pm_sh[tid] = u64max(pm_sh[tid], pm_sh[tid + off]);
        __syncthreads();
    }
    float value; int fi;
    unpack_vi(pm_sh[0], &value, &fi);
    int ai = fi >> 14;
    int ti = fi & (T_DIM - 1);
    int pos_idx = value > 0.0f ? ti : 0;
    int atom_idx = value > 0.0f ? ai : 0;

    float* e = emb + (seq * N_STEPS + 0) * 128;
    if (tid == 0) {
        e[0] = ((float)pos_idx / (float)(T_DIM - 1)) * 20.0f;
        e[1] = value;
        int nlo = ti - (K_DIM - 1); if (nlo < 0) nlo = 0;
        int nhi = ti + K_DIM;       if (nhi > T_DIM) nhi = T_DIM;
        dirty0[seq * 2 + 0] = nlo;
        dirty0[seq * 2 + 1] = nhi;
        w0slot[seq] = pm_sh[0];
    }
    if (tid >= 2 && tid < 2 + E_DIM) e[tid] = ae[atom_idx * E_DIM + tid - 2];
}

// ---------------------------------------------------------------------------
// persistent steps 1..15, R11 coordinator protocol (proven best):
//  blk 0..63:  compute blocks, LDS-resident residual half (staged from input
//              + winner0 applied locally). If dirty, compute tile -> dslot.
//              Poll per-(step,seq) winner slot (1 lane), apply locally.
//  blk 64:     coordinator: 1024-entry table, polls <=32 expected dslots,
//              reduces, writes emb row, publishes winner.
// After step 15: half-owner blocks reduce sum-of-squares in LDS and
// atomicAdd 2 commutative partials -> norm2[seq]. No global res at all.
__global__ __launch_bounds__(256) void k_inc(
    const float* __restrict__ a, const float* __restrict__ b,
    const float* __restrict__ du, const float* __restrict__ ae,
    float* __restrict__ emb, const unsigned long long* __restrict__ pmax,
    unsigned long long* __restrict__ dslots,
    unsigned long long* __restrict__ wslot,
    const unsigned long long* __restrict__ w0slot,
    const int* __restrict__ dirty0, float* __restrict__ norm2) {

    int seq = blockIdx.y;
    int blk = blockIdx.x;                 // 0..64
    int tid = threadIdx.x;

    if (blk == NCB) {
        // ================= coordinator =================
        __shared__ unsigned long long table[NPT];     // 8 KB
        __shared__ unsigned long long red4[4];
        for (int i = tid; i < NPT; i += 256) table[i] = pmax[seq * NPT + i];
        int lo = dirty0[seq * 2 + 0];
        int hi = dirty0[seq * 2 + 1];
        __syncthreads();

        for (int step = 1; step < N_STEPS; step++) {
            int T0 = lo >> 8, T1 = T0 + 1;
            bool hasT1 = (T1 < NTT) && (T1 * TT < hi);
            if (tid < 2 * NAT) {
                int at = tid >> 1, w = tid & 1;
                if (w == 0 || hasT1) {
                    const unsigned long long* sp =
                        &dslots[((step - 1) * NSEQ + seq) * (2 * NAT) + tid];
                    unsigned long long v = __hip_atomic_load(sp, __ATOMIC_RELAXED,
                                                             __HIP_MEMORY_SCOPE_AGENT);
                    while (v == 0ULL) {
                        __builtin_amdgcn_s_sleep(1);
                        v = __hip_atomic_load(sp, __ATOMIC_RELAXED,
                                              __HIP_MEMORY_SCOPE_AGENT);
                    }
                    table[at * NTT + (w ? T1 : T0)] = v;
                }
            }
            __syncthreads();
            unsigned long long m = u64max(table[tid], table[tid + 256]);
            m = u64max(m, u64max(table[tid + 512], table[tid + 768]));
            #pragma unroll
            for (int off = 32; off > 0; off >>= 1)
                m = u64max(m, __shfl_down(m, off));
            if ((tid & 63) == 0) red4[tid >> 6] = m;
            __syncthreads();
            unsigned long long w;
            if (tid == 0) {
                w = red4[0];
                #pragma unroll
                for (int j = 1; j < 4; j++) w = u64max(w, red4[j]);
                red4[0] = w;
                atomicExch(&wslot[(step - 1) * NSEQ + seq], w);
            }
            __syncthreads();
            w = red4[0];
            float value; int fi;
            unpack_vi(w, &value, &fi);
            int ti = fi & (T_DIM - 1);
            int ai = fi >> 14;
            int pos_idx = value > 0.0f ? ti : 0;
            int atom_idx = value > 0.0f ? ai : 0;
            float* e = emb + (seq * N_STEPS + step) * 128;
            if (tid == 0) {
                e[0] = ((float)pos_idx / (float)(T_DIM - 1)) * 20.0f;
                e[1] = value;
            }
            if (tid >= 2 && tid < 128) e[tid] = ae[atom_idx * E_DIM + tid - 2];
            lo = ti - (K_DIM - 1); if (lo < 0) lo = 0;
            hi = ti + K_DIM;       if (hi > T_DIM) hi = T_DIM;
        }
        return;
    }

    // ================= compute block =================
    int atile = blk >> 2;                 // 0..15
    int half = (blk >> 1) & 1;
    int par = blk & 1;
    int a_base = atile * ATI;
    int base = half * HB;

    __shared__ float resL[RL_PAD];             // ~34 KB padded local residual
    __shared__ unsigned long long red4[4];
    __shared__ unsigned long long wsh;
    __shared__ float w0v_s; __shared__ int w0t_s, w0a_s;
    __shared__ float snorm[256];

    if (tid == 0) {
        float v; int fi;
        unpack_vi(w0slot[seq], &v, &fi);
        w0v_s = v; w0t_s = fi & (T_DIM - 1); w0a_s = fi >> 14;
    }
    __syncthreads();
    float w0v = w0v_s; int w0t = w0t_s, w0a = w0a_s;

    // stage local residual from input, apply step-0 update locally
    const float* x = (seq < 2 ? a : b) + (seq & 1) * T_DIM;
    for (int i = tid; i < RL_LEN; i += 256) {
        int t = base - 64 + i;
        float v = 0.0f;
        if (t >= 0 && t < T_DIM) {
            v = x[t];
            int dk = t - (w0t - K_DIM / 2);
            if (dk >= 0 && dk < K_DIM)
                v = __fsub_rn(v, __fmul_rn(w0v, du[w0a * K_DIM + dk]));
        }
        resL[PIDX(i)] = v;
    }
    int lo = dirty0[seq * 2 + 0];
    int hi = dirty0[seq * 2 + 1];
    __syncthreads();

    for (int step = 1; step < N_STEPS; step++) {
        int T0 = lo >> 8, T1 = T0 + 1;
        int cand = -1;
        if (((T0 & 1) == par) && ((T0 >> 5) == half)) cand = T0;
        else if (T1 < NTT && ((T1 & 1) == par) && ((T1 >> 5) == half) &&
                 T1 * TT < hi) cand = T1;

        if (cand >= 0) {
            int t0 = cand * TT;
            int tg = tid & 63;
            int ag = __builtin_amdgcn_readfirstlane(tid >> 6);
            unsigned long long p = tile_compute(
                du + (a_base + ag * 2) * K_DIM, resL,
                (t0 - base) + 4 * tg, a_base + ag * 2, t0 + 4 * tg, tid, red4);
            if (tid == 0)
                atomicExch(&dslots[((step - 1) * NSEQ + seq) * (2 * NAT) +
                                   atile * 2 + (cand == T1 ? 1 : 0)], p);
        }
        if (tid == 0) {
            const unsigned long long* sp = &wslot[(step - 1) * NSEQ + seq];
            unsigned long long v = __hip_atomic_load(sp, __ATOMIC_RELAXED,
                                                     __HIP_MEMORY_SCOPE_AGENT);
            while (v == 0ULL) {
                __builtin_amdgcn_s_sleep(2);
                v = __hip_atomic_load(sp, __ATOMIC_RELAXED,
                                      __HIP_MEMORY_SCOPE_AGENT);
            }
            wsh = v;
        }
        __syncthreads();

        float value; int fi;
        unpack_vi(wsh, &value, &fi);
        int ti = fi & (T_DIM - 1);
        int ai = fi >> 14;
        // apply winner's update to local residual (mul-then-sub, step order)
        if (tid < 128) {
            int t = ti - K_DIM / 2 + tid;
            if (t >= 0 && t < T_DIM) {
                int L = t - base + 64;
                if (L >= 0 && L < RL_LEN) {
                    float r = resL[PIDX(L)];
                    resL[PIDX(L)] = __fsub_rn(r, __fmul_rn(value, du[ai * K_DIM + tid]));
                }
            }
        }
        __syncthreads();
        lo = ti - (K_DIM - 1); if (lo < 0) lo = 0;
        hi = ti + K_DIM;       if (hi > T_DIM) hi = T_DIM;
    }

    // norm^2 partial: one block per (seq, half); 2 commutative atomicAdds/seq
    if (atile == 0 && par == 0) {
        float s = 0.0f;
        for (int t = tid; t < HB; t += 256) {
            float v = resL[PIDX(t + 64)];
            s = fmaf(v, v, s);
        }
        snorm[tid] = s;
        __syncthreads();
        for (int off = 128; off > 0; off >>= 1) {
            if (tid < off) snorm[tid] += snorm[tid + off];
            __syncthreads();
        }
        if (tid == 0) atomicAdd(&norm2[seq], snorm[0]);
    }
}

// ---------------------------------------------------------------------------
// keys + ordering + MSE + norm-|diff|; 1 block x 1024 threads
__global__ __launch_bounds__(1024) void k_tail(
    const float* __restrict__ emb, const float* __restrict__ proj,
    const float* __restrict__ norm2, float* __restrict__ out) {
    int tid = threadIdx.x;
    __shared__ float sh[1024];
    __shared__ float norms[NSEQ];
    __shared__ float keys[NSEQ][N_STEPS];
    __shared__ int   order[NSEQ][N_STEPS];

    if (tid < NSEQ) norms[tid] = sqrtf(norm2[tid]);
    {
        int pair = tid >> 4;
        int seq = pair >> 4, st = pair & 15;
        int ln = tid & 15;
        const float* e = emb + (seq * N_STEPS + st) * 128 + ln * 8;
        const float* pr = proj + ln * 8;
        float kk = 0.0f;
        #pragma unroll
        for (int dd = 0; dd < 8; dd++) kk = fmaf(e[dd], pr[dd], kk);
        sh[tid] = kk;
        __syncthreads();
        for (int off = 8; off > 0; off >>= 1) {
            if (ln < off) sh[tid] += sh[tid + off];
            __syncthreads();
        }
        if (ln == 0) keys[seq][st] = sh[tid];
        __syncthreads();
    }
    if (tid < NSEQ) {
        int ord[N_STEPS];
        for (int i = 0; i < N_STEPS; i++) ord[i] = i;
        for (int i = 1; i < N_STEPS; i++) {
            int oi = ord[i];
            float kv = keys[tid][oi];
            int j = i - 1;
            while (j >= 0 && keys[tid][ord[j]] > kv) { ord[j + 1] = ord[j]; j--; }
            ord[j + 1] = oi;
        }
        for (int i = 0; i < N_STEPS; i++) order[tid][i] = ord[i];
    }
    __syncthreads();
    float s = 0.0f;
    #pragma unroll
    for (int t = 0; t < 4; t++) {
        int idx = tid + t * 1024;
        int bq = idx >> 11;
        int st = (idx >> 7) & 15;
        int dd = idx & 127;
        float va = emb[((bq    ) * N_STEPS + order[bq    ][st]) * 128 + dd];
        float vb = emb[((2 + bq) * N_STEPS + order[2 + bq][st]) * 128 + dd];
        float df = va - vb;
        s = fmaf(df, df, s);
    }
    sh[tid] = s;
    __syncthreads();
    for (int off = 512; off > 0; off >>= 1) {
        if (tid < off) sh[tid] += sh[tid + off];
        __syncthreads();
    }
    if (tid == 0) {
        float mse = sh[0] / 4096.0f;
        float mad = 0.5f * (fabsf(norms[0] - norms[2]) + fabsf(norms[1] - norms[3]));
        out[0] = mse + mad;
    }
}

// ---------------------------------------------------------------------------
extern "C" void kernel_launch(void* const* d_in, const int* in_sizes, int n_in,
                              void* d_out, int out_size, void* d_ws, size_t ws_size,
                              hipStream_t stream) {
    const float* a    = (const float*)d_in[0];
    const float* b    = (const float*)d_in[1];
    const float* d    = (const float*)d_in[2];
    const float* ae   = (const float*)d_in[3];
    const float* proj = (const float*)d_in[4];
    float* out = (float*)d_out;

    float* ws  = (float*)d_ws;
    float* du  = ws;                              // 16384 f
    float* emb = du + A_DIM * K_DIM;              // 8192 f
    unsigned long long* pmax   = (unsigned long long*)(emb + NSEQ * N_STEPS * 128); // 4096 u64
    unsigned long long* dslots = pmax + NSEQ * NPT;                    // 1920 u64
    unsigned long long* wslot  = dslots + (N_STEPS - 1) * NSEQ * 2 * NAT; // 60 u64
    unsigned long long* w0slot = wslot + (N_STEPS - 1) * NSEQ;         // 4 u64
    int* cnt    = (int*)(w0slot + NSEQ);                               // 4
    int* dirty0 = cnt + NSEQ;                                          // 8
    float* norm2 = (float*)(dirty0 + 2 * NSEQ);                        // 4

    k_prep<<<129, 256, 0, stream>>>(d, du, dslots, cnt, norm2);

    dim3 gfull(NPT, NSEQ);
    k_step_full<<<gfull, 256, 0, stream>>>(a, b, du, ae, emb, pmax, cnt,
                                           dirty0, w0slot);

    dim3 ginc(NCB + 1, NSEQ);
    k_inc<<<ginc, 256, 0, stream>>>(a, b, du, ae, emb, pmax, dslots, wslot,
                                    w0slot, dirty0, norm2);

    k_tail<<<1, 1024, 0, stream>>>(emb, proj, norm2, out);
}

// Round 14
// 214.549 us; speedup vs baseline: 1.2406x; 1.1567x over previous
//
#include <hip/hip_runtime.h>
#include <math.h>

#define T_DIM 16384
#define A_DIM 128
#define K_DIM 128
#define N_STEPS 16
#define E_DIM 126
#define NSEQ 4

// step0: 16-atom x 256-t tiles -> 8 atiles x 64 ttiles = 512 tiles/seq
#define NPT0 512
// inc: 8-atom tiles, 16 atiles x 2 halves x 2 parities = 64 compute blocks/seq
#define NAT8 16
#define TT 256
#define NTT 64
#define HB 8192
#define RL_LEN 8319     // [base-64, base+8255]
#define SS_LEN 383
#define SPAD 16         // mailbox stride: 16 u64 = 128 B (one line per slot)

#define PIDX(i) ((i) + ((i) >> 5))   // +1 pad per 32 dwords: conflict-free

#define NB_STEP0 (NPT0 * NSEQ)       // 2048
#define NB_INC   (65 * NSEQ)         // 260
#define NB_TOTAL (NB_STEP0 + NB_INC + 1)

#define SM_U64 4448                  // 35584 B shared arena (union of roles)

// order-preserving pack: bigger u64 == (bigger value, then smaller flat idx).
__device__ inline unsigned long long pack_vi(float v, int fi) {
    unsigned int b = __float_as_uint(v);
    b = (b & 0x80000000u) ? ~b : (b | 0x80000000u);
    return ((unsigned long long)b << 32) | (unsigned int)(~fi);
}
__device__ inline void unpack_vi(unsigned long long p, float* v, int* fi) {
    unsigned int lo = (unsigned int)(p & 0xffffffffu);
    unsigned int b = (unsigned int)(p >> 32);
    unsigned int fb = (b & 0x80000000u) ? (b & 0x7fffffffu) : ~b;
    *v = __uint_as_float(fb);
    *fi = (int)(~lo);
}
__device__ inline unsigned long long u64max(unsigned long long a, unsigned long long b) {
    return a > b ? a : b;
}
__device__ inline unsigned long long pollu64(const unsigned long long* p) {
    unsigned long long v = __hip_atomic_load(p, __ATOMIC_RELAXED,
                                             __HIP_MEMORY_SCOPE_AGENT);
    while (v == 0ULL) {
        __builtin_amdgcn_s_sleep(1);
        v = __hip_atomic_load(p, __ATOMIC_RELAXED, __HIP_MEMORY_SCOPE_AGENT);
    }
    return v;
}

// ---------------------------------------------------------------------------
// arena u64 layout: pmax[0,2048) | dslots[2048,32768) (15*4*32 slots * SPAD)
// | wslot[32768,33728) ((15*4)*SPAD) | w0slot[33728,33792) (4*SPAD)
// | ctrl ints at +33792: cnt[seq*32], done at [128], norm2 floats at [160+seq*32]
__global__ __launch_bounds__(256) void k_prep(
    const float* __restrict__ d, float* __restrict__ du,
    unsigned long long* __restrict__ arena) {
    int blk = blockIdx.x, tid = threadIdx.x;
    if (blk < 128) {
        __shared__ float s[128];
        float v = 0.0f;
        if (tid < 128) { v = d[blk * K_DIM + tid]; s[tid] = v * v; }
        __syncthreads();
        for (int off = 64; off > 0; off >>= 1) {
            if (tid < off) s[tid] += s[tid + off];
            __syncthreads();
        }
        if (tid < 128) du[blk * K_DIM + tid] = v / (sqrtf(s[0]) + 1e-8f);
    } else {
        int zb = blk - 128;                       // 0..63
        for (int i = zb * 256 + tid; i < 31744; i += 64 * 256)
            arena[2048 + i] = 0ULL;
        if (blk == 128) {
            int* ctrl = (int*)(arena + 33792);
            if (tid < NSEQ) {
                ctrl[tid * 32] = 0;                         // cnt
                ((float*)ctrl)[160 + tid * 32] = 0.0f;      // norm2
            }
            if (tid == 4) ctrl[128] = 0;                    // done
        }
    }
}

// ---------------------------------------------------------------------------
// 16a x 256t engine (R10/R11-proven bit-exact): du via wave-uniform s_load
// float4 (4 atoms/wave); res via padded b32 sliding window. k ascending.
__device__ inline unsigned long long tile16(
    const float* __restrict__ duP, const float* __restrict__ rsh,
    int L0, int a_lo, int t_lo, int tid, unsigned long long* red4) {
    float acc[4][4];
    #pragma unroll
    for (int i = 0; i < 4; i++)
        #pragma unroll
        for (int j = 0; j < 4; j++) acc[i][j] = 0.0f;
    float r[8];
    #pragma unroll
    for (int m = 0; m < 8; m++) r[m] = rsh[PIDX(L0 + m)];
    #pragma unroll 4
    for (int k = 0; k < K_DIM; k += 4) {
        float dA[4][4];
        #pragma unroll
        for (int i = 0; i < 4; i++)
            *(float4*)dA[i] = *(const float4*)(duP + i * K_DIM + k);
        #pragma unroll
        for (int dk = 0; dk < 4; dk++) {
            #pragma unroll
            for (int i = 0; i < 4; i++) {
                float s = dA[i][dk];
                #pragma unroll
                for (int j = 0; j < 4; j++)
                    acc[i][j] = fmaf(s, r[j + dk], acc[i][j]);
            }
        }
        r[0] = r[4]; r[1] = r[5]; r[2] = r[6]; r[3] = r[7];
        #pragma unroll
        for (int m = 0; m < 4; m++) r[4 + m] = rsh[PIDX(L0 + k + 8 + m)];
    }
    float bv = -INFINITY;
    int bi = 0x7fffffff;
    #pragma unroll
    for (int i = 0; i < 4; i++) {
        int aa = a_lo + i;
        #pragma unroll
        for (int j = 0; j < 4; j++) {
            int fi = aa * T_DIM + t_lo + j;
            float v = acc[i][j];
            if (v > bv || (v == bv && fi < bi)) { bv = v; bi = fi; }
        }
    }
    #pragma unroll
    for (int off = 32; off > 0; off >>= 1) {
        float v2 = __shfl_down(bv, off);
        int   i2 = __shfl_down(bi, off);
        if (v2 > bv || (v2 == bv && i2 < bi)) { bv = v2; bi = i2; }
    }
    if ((tid & 63) == 0) red4[tid >> 6] = pack_vi(bv, bi);
    __syncthreads();
    if (tid == 0) {
        unsigned long long m = red4[0];
        #pragma unroll
        for (int w = 1; w < 4; w++) m = u64max(m, red4[w]);
        red4[0] = m;
    }
    __syncthreads();
    return red4[0];
}

// 8a x 256t engine (R13-proven bit-exact): 2 atoms/wave.
__device__ inline unsigned long long tile8(
    const float* __restrict__ duP, const float* __restrict__ rsh,
    int L0, int a_lo, int t_lo, int tid, unsigned long long* red4) {
    float acc[2][4];
    #pragma unroll
    for (int i = 0; i < 2; i++)
        #pragma unroll
        for (int j = 0; j < 4; j++) acc[i][j] = 0.0f;
    float r[8];
    #pragma unroll
    for (int m = 0; m < 8; m++) r[m] = rsh[PIDX(L0 + m)];
    #pragma unroll 4
    for (int k = 0; k < K_DIM; k += 4) {
        float dA[2][4];
        #pragma unroll
        for (int i = 0; i < 2; i++)
            *(float4*)dA[i] = *(const float4*)(duP + i * K_DIM + k);
        #pragma unroll
        for (int dk = 0; dk < 4; dk++) {
            #pragma unroll
            for (int i = 0; i < 2; i++) {
                float s = dA[i][dk];
                #pragma unroll
                for (int j = 0; j < 4; j++)
                    acc[i][j] = fmaf(s, r[j + dk], acc[i][j]);
            }
        }
        r[0] = r[4]; r[1] = r[5]; r[2] = r[6]; r[3] = r[7];
        #pragma unroll
        for (int m = 0; m < 4; m++) r[4 + m] = rsh[PIDX(L0 + k + 8 + m)];
    }
    float bv = -INFINITY;
    int bi = 0x7fffffff;
    #pragma unroll
    for (int i = 0; i < 2; i++) {
        int aa = a_lo + i;
        #pragma unroll
        for (int j = 0; j < 4; j++) {
            int fi = aa * T_DIM + t_lo + j;
            float v = acc[i][j];
            if (v > bv || (v == bv && fi < bi)) { bv = v; bi = fi; }
        }
    }
    #pragma unroll
    for (int off = 32; off > 0; off >>= 1) {
        float v2 = __shfl_down(bv, off);
        int   i2 = __shfl_down(bi, off);
        if (v2 > bv || (v2 == bv && i2 < bi)) { bv = v2; bi = i2; }
    }
    if ((tid & 63) == 0) red4[tid >> 6] = pack_vi(bv, bi);
    __syncthreads();
    if (tid == 0) {
        unsigned long long m = red4[0];
        #pragma unroll
        for (int w = 1; w < 4; w++) m = u64max(m, red4[w]);
        red4[0] = m;
    }
    __syncthreads();
    return red4[0];
}

// ---------------------------------------------------------------------------
// One fused kernel: step0 (2048 blocks) + persistent inc (260) + tail (1).
__global__ __launch_bounds__(256) void k_mega(
    const float* __restrict__ a, const float* __restrict__ b,
    const float* __restrict__ du, const float* __restrict__ ae,
    const float* __restrict__ proj, float* __restrict__ emb,
    unsigned long long* __restrict__ arena, float* __restrict__ out) {

    __shared__ unsigned long long SMEM[SM_U64];
    unsigned long long* pmax = arena;
    unsigned long long* dsl  = arena + 2048;
    unsigned long long* wsl  = arena + 32768;
    unsigned long long* w0   = arena + 33728;
    int*   cnt   = (int*)(arena + 33792);
    int*   done  = cnt + 128;
    float* norm2 = (float*)cnt + 160;

    int blk = blockIdx.x;
    int tid = threadIdx.x;

    if (blk < NB_STEP0) {
        // ===================== step0 role =====================
        int seq = blk >> 9;
        int idx = blk & 511;
        int a_base = (idx >> 6) * 16;
        int t0 = (idx & 63) * TT;
        float* rsh = (float*)SMEM;                       // PIDX<=394
        unsigned long long* pm_sh = SMEM + 256;
        unsigned long long* red4  = SMEM + 512;
        int* flag = (int*)(SMEM + 516);

        const float* x = (seq < 2 ? a : b) + (seq & 1) * T_DIM;
        for (int i = tid; i < SS_LEN; i += 256) {
            int t = t0 - 64 + i;
            rsh[PIDX(i)] = (t >= 0 && t < T_DIM) ? x[t] : 0.0f;
        }
        __syncthreads();
        int tg = tid & 63;
        int ag = __builtin_amdgcn_readfirstlane(tid >> 6);
        unsigned long long p = tile16(du + (a_base + ag * 4) * K_DIM, rsh,
                                      4 * tg, a_base + ag * 4, t0 + 4 * tg,
                                      tid, red4);
        if (tid == 0) {
            pmax[seq * NPT0 + idx] = p;
            __threadfence();
            flag[0] = (atomicAdd(&cnt[seq * 32], 1) == NPT0 - 1);
        }
        __syncthreads();
        if (!flag[0]) return;

        __threadfence();
        pm_sh[tid] = u64max(pmax[seq * NPT0 + tid], pmax[seq * NPT0 + 256 + tid]);
        __syncthreads();
        for (int off = 128; off > 0; off >>= 1) {
            if (tid < off) pm_sh[tid] = u64max(pm_sh[tid], pm_sh[tid + off]);
            __syncthreads();
        }
        float value; int fi;
        unpack_vi(pm_sh[0], &value, &fi);
        int ai = fi >> 14, ti = fi & (T_DIM - 1);
        int pos_idx = value > 0.0f ? ti : 0;
        int atom_idx = value > 0.0f ? ai : 0;
        float* e = emb + (seq * N_STEPS + 0) * 128;
        if (tid == 0) {
            e[0] = ((float)pos_idx / (float)(T_DIM - 1)) * 20.0f;
            e[1] = value;
        }
        if (tid >= 2 && tid < 2 + E_DIM) e[tid] = ae[atom_idx * E_DIM + tid - 2];
        __syncthreads();
        __threadfence();
        if (tid == 0) atomicExch(&w0[seq * SPAD], pm_sh[0]);
        return;
    }

    if (blk < NB_STEP0 + NB_INC) {
        int r = blk - NB_STEP0;
        int seq = r / 65;
        int sub = r - seq * 65;

        if (sub == 64) {
            // ===================== coordinator =====================
            unsigned long long* table   = SMEM;          // 512
            unsigned long long* poll_sh = SMEM + 512;    // 32
            unsigned long long* red4    = SMEM + 548;
            unsigned long long* wbc     = SMEM + 552;

            if (tid == 0) wbc[0] = pollu64(&w0[seq * SPAD]);
            __syncthreads();
            __threadfence();   // acquire: pmax writes ordered before w0 publish
            for (int i = tid; i < NPT0; i += 256) table[i] = pmax[seq * NPT0 + i];
            float v0; int fi0;
            unpack_vi(wbc[0], &v0, &fi0);
            int ti = fi0 & (T_DIM - 1);
            int lo = ti - 127; if (lo < 0) lo = 0;
            int hi = ti + 128; if (hi > T_DIM) hi = T_DIM;
            __syncthreads();

            for (int step = 1; step < N_STEPS; step++) {
                int T0 = lo >> 8, T1 = T0 + 1;
                bool hasT1 = (T1 < NTT) && (T1 * TT < hi);
                if (tid < 32) {
                    if (((tid & 1) == 0) || hasT1)
                        poll_sh[tid] = pollu64(
                            &dsl[(((step - 1) * NSEQ + seq) * 32 + tid) * SPAD]);
                }
                __syncthreads();
                if (tid < 16) {
                    int at16 = tid >> 1, ts = tid & 1;
                    if (ts == 0 || hasT1)
                        table[at16 * 64 + (ts ? T1 : T0)] =
                            u64max(poll_sh[at16 * 4 + ts], poll_sh[at16 * 4 + 2 + ts]);
                }
                __syncthreads();
                unsigned long long m = u64max(table[tid], table[tid + 256]);
                #pragma unroll
                for (int off = 32; off > 0; off >>= 1)
                    m = u64max(m, __shfl_down(m, off));
                if ((tid & 63) == 0) red4[tid >> 6] = m;
                __syncthreads();
                if (tid == 0) {
                    unsigned long long w = red4[0];
                    #pragma unroll
                    for (int j = 1; j < 4; j++) w = u64max(w, red4[j]);
                    red4[0] = w;
                    atomicExch(&wsl[((step - 1) * NSEQ + seq) * SPAD], w);
                }
                __syncthreads();
                float value; int fi;
                unpack_vi(red4[0], &value, &fi);
                int wt = fi & (T_DIM - 1);
                int wa = fi >> 14;
                int pos_idx = value > 0.0f ? wt : 0;
                int atom_idx = value > 0.0f ? wa : 0;
                float* e = emb + (seq * N_STEPS + step) * 128;
                if (tid == 0) {
                    e[0] = ((float)pos_idx / (float)(T_DIM - 1)) * 20.0f;
                    e[1] = value;
                }
                if (tid >= 2 && tid < 128) e[tid] = ae[atom_idx * E_DIM + tid - 2];
                lo = wt - 127; if (lo < 0) lo = 0;
                hi = wt + 128; if (hi > T_DIM) hi = T_DIM;
            }
            __syncthreads();
            __threadfence();
            if (tid == 0) atomicAdd(done, 1);
            return;
        }

        // ===================== inc compute block =====================
        int atile = sub >> 2;                 // 0..15
        int half = (sub >> 1) & 1;
        int par = sub & 1;
        int a_base = atile * 8;
        int base = half * HB;
        float* resL = (float*)SMEM;                         // PIDX big
        unsigned long long* red4 = SMEM + 4304;
        unsigned long long* wshp = SMEM + 4308;
        float* snorm = (float*)(SMEM + 4320);               // 256 f

        const float* x = (seq < 2 ? a : b) + (seq & 1) * T_DIM;
        for (int i = tid; i < RL_LEN; i += 256) {           // overlaps step0
            int t = base - 64 + i;
            resL[PIDX(i)] = (t >= 0 && t < T_DIM) ? x[t] : 0.0f;
        }
        if (tid == 0) wshp[0] = pollu64(&w0[seq * SPAD]);
        __syncthreads();
        float v0; int fi0;
        unpack_vi(wshp[0], &v0, &fi0);
        int ti0 = fi0 & (T_DIM - 1), ai0 = fi0 >> 14;
        if (tid < 128) {                                    // apply step-0
            int t = ti0 - 64 + tid;
            if (t >= 0 && t < T_DIM) {
                int L = t - base + 64;
                if (L >= 0 && L < RL_LEN) {
                    float rr = resL[PIDX(L)];
                    resL[PIDX(L)] = __fsub_rn(rr, __fmul_rn(v0, du[ai0 * K_DIM + tid]));
                }
            }
        }
        __syncthreads();
        int lo = ti0 - 127; if (lo < 0) lo = 0;
        int hi = ti0 + 128; if (hi > T_DIM) hi = T_DIM;

        for (int step = 1; step < N_STEPS; step++) {
            int T0 = lo >> 8, T1 = T0 + 1;
            int cand = -1;
            if (((T0 & 1) == par) && ((T0 >> 5) == half)) cand = T0;
            else if (T1 < NTT && ((T1 & 1) == par) && ((T1 >> 5) == half) &&
                     T1 * TT < hi) cand = T1;

            if (cand >= 0) {
                int t0 = cand * TT;
                int tg = tid & 63;
                int ag = __builtin_amdgcn_readfirstlane(tid >> 6);
                unsigned long long p = tile8(
                    du + (a_base + ag * 2) * K_DIM, resL,
                    (t0 - base) + 4 * tg, a_base + ag * 2, t0 + 4 * tg, tid, red4);
                if (tid == 0)
                    atomicExch(&dsl[(((step - 1) * NSEQ + seq) * 32 +
                                     atile * 2 + (cand == T1 ? 1 : 0)) * SPAD], p);
            }
            if (tid == 0) wshp[0] = pollu64(&wsl[((step - 1) * NSEQ + seq) * SPAD]);
            __syncthreads();
            float value; int fi;
            unpack_vi(wshp[0], &value, &fi);
            int wt = fi & (T_DIM - 1);
            int wa = fi >> 14;
            if (tid < 128) {
                int t = wt - 64 + tid;
                if (t >= 0 && t < T_DIM) {
                    int L = t - base + 64;
                    if (L >= 0 && L < RL_LEN) {
                        float rr = resL[PIDX(L)];
                        resL[PIDX(L)] = __fsub_rn(rr, __fmul_rn(value, du[wa * K_DIM + tid]));
                    }
                }
            }
            __syncthreads();
            lo = wt - 127; if (lo < 0) lo = 0;
            hi = wt + 128; if (hi > T_DIM) hi = T_DIM;
        }

        if (atile == 0 && par == 0) {       // norm^2 partial for this half
            float s = 0.0f;
            for (int t = tid; t < HB; t += 256) {
                float v = resL[PIDX(t + 64)];
                s = fmaf(v, v, s);
            }
            snorm[tid] = s;
            __syncthreads();
            for (int off = 128; off > 0; off >>= 1) {
                if (tid < off) snorm[tid] += snorm[tid + off];
                __syncthreads();
            }
            if (tid == 0) {
                float old = atomicAdd(&norm2[seq * 32], snorm[0]);
                if (__float_as_uint(old) != 0xFFFFFFFFu)   // dep: order add after add
                    atomicAdd(done, 1);
            }
        }
        return;
    }

    // ===================== tail role =====================
    {
        float* keys  = (float*)SMEM;               // 64
        int*   order = (int*)(SMEM + 32);          // 64
        float* sh    = (float*)(SMEM + 64);        // 256
        float* norms = (float*)(SMEM + 192);       // 4

        if (tid == 0) {
            int c = __hip_atomic_load(done, __ATOMIC_RELAXED, __HIP_MEMORY_SCOPE_AGENT);
            while (c < 12) {
                __builtin_amdgcn_s_sleep(8);
                c = __hip_atomic_load(done, __ATOMIC_RELAXED, __HIP_MEMORY_SCOPE_AGENT);
            }
        }
        __syncthreads();
        __threadfence();   // acquire: emb + norm2 writes

        if (tid < NSEQ)
            norms[tid] = sqrtf(__hip_atomic_load(&norm2[tid * 32], __ATOMIC_RELAXED,
                                                 __HIP_MEMORY_SCOPE_AGENT));
        if (tid < 64) {
            int seq = tid >> 4, st = tid & 15;
            const float* e = emb + (seq * N_STEPS + st) * 128;
            float kk = 0.0f;
            for (int dd = 0; dd < 128; dd++) kk = fmaf(e[dd], proj[dd], kk);
            keys[tid] = kk;
        }
        __syncthreads();
        if (tid < NSEQ) {
            int ord[N_STEPS];
            for (int i = 0; i < N_STEPS; i++) ord[i] = i;
            for (int i = 1; i < N_STEPS; i++) {     // stable ascending
                int oi = ord[i];
                float kv = keys[tid * N_STEPS + oi];
                int j = i - 1;
                while (j >= 0 && keys[tid * N_STEPS + ord[j]] > kv) {
                    ord[j + 1] = ord[j]; j--;
                }
                ord[j + 1] = oi;
            }
            for (int i = 0; i < N_STEPS; i++) order[tid * N_STEPS + i] = ord[i];
        }
        __syncthreads();
        float s = 0.0f;
        #pragma unroll
        for (int t = 0; t < 16; t++) {
            int idx = tid + t * 256;
            int bq = idx >> 11;
            int st = (idx >> 7) & 15;
            int dd = idx & 127;
            float va = emb[((bq    ) * N_STEPS + order[bq * N_STEPS + st]) * 128 + dd];
            float vb = emb[((2 + bq) * N_STEPS + order[(2 + bq) * N_STEPS + st]) * 128 + dd];
            float df = va - vb;
            s = fmaf(df, df, s);
        }
        sh[tid] = s;
        __syncthreads();
        for (int off = 128; off > 0; off >>= 1) {
            if (tid < off) sh[tid] += sh[tid + off];
            __syncthreads();
        }
        if (tid == 0) {
            float mse = sh[0] / 4096.0f;
            float mad = 0.5f * (fabsf(norms[0] - norms[2]) + fabsf(norms[1] - norms[3]));
            out[0] = mse + mad;
        }
    }
}

// ---------------------------------------------------------------------------
extern "C" void kernel_launch(void* const* d_in, const int* in_sizes, int n_in,
                              void* d_out, int out_size, void* d_ws, size_t ws_size,
                              hipStream_t stream) {
    const float* a    = (const float*)d_in[0];
    const float* b    = (const float*)d_in[1];
    const float* d    = (const float*)d_in[2];
    const float* ae   = (const float*)d_in[3];
    const float* proj = (const float*)d_in[4];
    float* out = (float*)d_out;

    float* ws  = (float*)d_ws;
    float* du  = ws;                              // 16384 f
    float* emb = du + A_DIM * K_DIM;              // 8192 f
    unsigned long long* arena = (unsigned long long*)(emb + NSEQ * N_STEPS * 128);

    k_prep<<<192, 256, 0, stream>>>(d, du, arena);
    k_mega<<<NB_TOTAL, 256, 0, stream>>>(a, b, du, ae, proj, emb, arena, out);
}